// Round 12
// baseline (80.061 us; speedup 1.0000x reference)
//
#include <hip/hip_runtime.h>

#define DMODEL 1024
#define DHEAD 128
#define CHUNK 128
#define NCHUNK 32

typedef __attribute__((ext_vector_type(4))) float f32x4;
typedef __attribute__((ext_vector_type(8))) short bf16x8;

__device__ __forceinline__ unsigned short f2bf(float f) {
  union { float f; unsigned u; } v; v.f = f;
  unsigned r = v.u + 0x7FFF + ((v.u >> 16) & 1);   // RNE
  return (unsigned short)(r >> 16);
}
__device__ __forceinline__ float bf2f(unsigned short h) {
  union { unsigned u; float f; } v; v.u = ((unsigned)h) << 16;
  return v.f;
}
__device__ __forceinline__ unsigned cvtpk(float lo, float hi) {
  unsigned r;
  asm("v_cvt_pk_bf16_f32 %0, %1, %2" : "=v"(r) : "v"(lo), "v"(hi));
  return r;
}
__device__ __forceinline__ void gload16(const void* g, void* l) {
  __builtin_amdgcn_global_load_lds(
      (const __attribute__((address_space(1))) unsigned int*)g,
      (__attribute__((address_space(3))) unsigned int*)l, 16, 0, 0);
}

// ---------------- K0: W -> W^T bf16 [which][n][k] ----------------
__global__ __launch_bounds__(256) void transpose_w_kernel(
    const float* __restrict__ Wq, const float* __restrict__ Wk,
    const float* __restrict__ Wv, unsigned short* __restrict__ WT) {
  int id = blockIdx.x * 256 + threadIdx.x;
  int w = id >> 17;
  int rem = id & 131071;
  int n = rem >> 10;
  int k = rem & 1023;
  const float* W = (w == 0) ? Wq : (w == 1) ? Wk : Wv;
  WT[id] = f2bf(W[(size_t)k * DHEAD + n]);
}

// ---------------- K1: FUSED projection + phi, T4 pipeline ----------------
// 1024 blocks: BM=32, BN=64 (n-split 2), BK=64, 256 threads (4 waves).
// x: LDS double-buffer (2x8 KB) via global_load_lds, counted vmcnt(8).
// W: per-lane register loads straight from L2 (no LDS, compiler-tracked).
__global__ __launch_bounds__(256) void proj_kernel(
    const float* __restrict__ x, const unsigned short* __restrict__ WT,
    unsigned short* __restrict__ phiQ, unsigned short* __restrict__ phiK,
    unsigned short* __restrict__ Vb) {
  const int bid = blockIdx.x;
  const int xcd = bid & 7;
  const int slot = bid >> 3;                 // 0..127
  const int n0 = (slot & 1) << 6;            // 0 or 64
  const int m0 = ((xcd << 6) | (slot >> 1)) << 5;   // 512 m-tiles of 32 rows

  __shared__ float xs[2][32][64];            // 16 KB total, swizzled

  const int tid = threadIdx.x;
  const int wave = tid >> 6;                 // owns n-tile `wave`
  const int lane = tid & 63;
  const int lrow = lane & 15, kgrp = lane >> 4;

  // this lane's B-fragment row (fixed); k walks
  const unsigned short* wrow =
      WT + (size_t)(n0 + wave * 16 + lrow) * DMODEL + kgrp * 8;

  f32x4 acc[3][2];
#pragma unroll
  for (int w3 = 0; w3 < 3; ++w3)
#pragma unroll
    for (int mi = 0; mi < 2; ++mi) acc[w3][mi] = (f32x4)0.0f;

  bf16x8 wreg[2][3][2];                      // [buf][w3][ks2] — statically indexed

#define STAGE_X(T)                                                        \
  {                                                                       \
    _Pragma("unroll")                                                     \
    for (int i = 0; i < 2; ++i) {                                         \
      int instr = i * 4 + wave;                                           \
      int row = instr * 4 + (lane >> 4);                                  \
      int slotc = lane & 15;                                              \
      int gcol = (slotc ^ (row & 7)) << 2;                                \
      gload16(&x[(size_t)(m0 + row) * DMODEL + (T) * 64 + gcol],          \
              (char*)xs[(T) & 1] + instr * 1024);                         \
    }                                                                     \
  }
#define LOAD_W(T)                                                         \
  {                                                                       \
    _Pragma("unroll")                                                     \
    for (int w3 = 0; w3 < 3; ++w3)                                        \
      _Pragma("unroll")                                                   \
      for (int ks2 = 0; ks2 < 2; ++ks2)                                   \
        wreg[(T) & 1][w3][ks2] = *reinterpret_cast<const bf16x8*>(        \
            wrow + (size_t)w3 * (DHEAD * DMODEL) + (T) * 64 + ks2 * 32);  \
  }

  STAGE_X(0);
  LOAD_W(0);

#pragma unroll
  for (int t = 0; t < 16; ++t) {
    if (t < 15) {
      STAGE_X(t + 1);
      LOAD_W(t + 1);
      asm volatile("s_waitcnt vmcnt(8)" ::: "memory");   // batch t landed; t+1 in flight
    } else {
      asm volatile("s_waitcnt vmcnt(0)" ::: "memory");
    }
    __builtin_amdgcn_sched_barrier(0);
    __builtin_amdgcn_s_barrier();
    __builtin_amdgcn_sched_barrier(0);

#pragma unroll
    for (int ks2 = 0; ks2 < 2; ++ks2) {
      bf16x8 af[2];
#pragma unroll
      for (int mi = 0; mi < 2; ++mi) {
        int arow = mi * 16 + lrow;
        int s0 = ks2 * 8 + kgrp * 2;
        const float4 f0 = *reinterpret_cast<const float4*>(
            &xs[t & 1][arow][(s0 ^ (arow & 7)) << 2]);
        const float4 f1 = *reinterpret_cast<const float4*>(
            &xs[t & 1][arow][((s0 + 1) ^ (arow & 7)) << 2]);
        union { unsigned u[4]; bf16x8 v; } p;
        p.u[0] = cvtpk(f0.x, f0.y);
        p.u[1] = cvtpk(f0.z, f0.w);
        p.u[2] = cvtpk(f1.x, f1.y);
        p.u[3] = cvtpk(f1.z, f1.w);
        af[mi] = p.v;
      }
#pragma unroll
      for (int w3 = 0; w3 < 3; ++w3)
#pragma unroll
        for (int mi = 0; mi < 2; ++mi)
          acc[w3][mi] = __builtin_amdgcn_mfma_f32_16x16x32_bf16(
              af[mi], wreg[t & 1][w3][ks2], acc[w3][mi], 0, 0, 0);
    }
    __builtin_amdgcn_sched_barrier(0);
    __builtin_amdgcn_s_barrier();            // protect xs[t&1] from x(t+2)
  }
#undef STAGE_X
#undef LOAD_W

  // epilogue: phi for q/k, plain for v; store bf16
#pragma unroll
  for (int w3 = 0; w3 < 3; ++w3) {
    unsigned short* outp = (w3 == 0) ? phiQ : (w3 == 1) ? phiK : Vb;
#pragma unroll
    for (int mi = 0; mi < 2; ++mi)
#pragma unroll
      for (int r = 0; r < 4; ++r) {
        int row = m0 + mi * 16 + kgrp * 4 + r;
        int col = n0 + wave * 16 + lrow;
        float v = acc[w3][mi][r];
        if (w3 < 2) v = (v > 0.0f) ? (v + 1.0f) : __expf(v);
        outp[(size_t)row * DHEAD + col] = f2bf(v);
      }
  }
}

// ---------------- K2: per-chunk KV^T = v^T @ k (dv-split), ks colsums ----------------
__global__ __launch_bounds__(256) void chunkkv_kernel(
    const unsigned short* __restrict__ phiK, const unsigned short* __restrict__ Vb,
    float* __restrict__ KVc, float* __restrict__ ksc) {
  const int c = blockIdx.x;
  const int yv = blockIdx.y;
  const size_t base = (size_t)c * CHUNK * DHEAD;
  __shared__ unsigned short kt[128][136];   // k^T [d][t] (full)
  __shared__ unsigned short vt[64][136];    // v^T rows yv*64..+64
  __shared__ float csum[2][128];
  const int tid = threadIdx.x;
  const int wave = tid >> 6, lane = tid & 63;
  const int lrow = lane & 15, kgrp = lane >> 4;

  {
    int t = tid & 127, dp = tid >> 7;
#pragma unroll
    for (int i = 0; i < 8; ++i) {
      int d0 = (dp + 2 * i) * 8;
      uint4 k4 = *reinterpret_cast<const uint4*>(&phiK[base + (size_t)t * DHEAD + d0]);
      const unsigned short* kp = reinterpret_cast<const unsigned short*>(&k4);
#pragma unroll
      for (int j = 0; j < 8; ++j) kt[d0 + j][t] = kp[j];
    }
#pragma unroll
    for (int i = 0; i < 4; ++i) {
      int dl = (dp + 2 * i) * 8;             // 0..63 local dv
      uint4 v4 = *reinterpret_cast<const uint4*>(
          &Vb[base + (size_t)t * DHEAD + yv * 64 + dl]);
      const unsigned short* vp = reinterpret_cast<const unsigned short*>(&v4);
#pragma unroll
      for (int j = 0; j < 8; ++j) vt[dl + j][t] = vp[j];
    }
  }
  __syncthreads();

  f32x4 acc[8];
#pragma unroll
  for (int j = 0; j < 8; ++j) acc[j] = (f32x4)0.0f;
#pragma unroll
  for (int ks = 0; ks < 4; ++ks) {
    int t0 = ks * 32 + kgrp * 8;
    bf16x8 afrag = *reinterpret_cast<const bf16x8*>(&vt[wave * 16 + lrow][t0]);
#pragma unroll
    for (int tc = 0; tc < 8; ++tc) {
      bf16x8 bfrag = *reinterpret_cast<const bf16x8*>(&kt[tc * 16 + lrow][t0]);
      acc[tc] = __builtin_amdgcn_mfma_f32_16x16x32_bf16(afrag, bfrag, acc[tc], 0, 0, 0);
    }
  }
  float* KVout = KVc + (size_t)c * (DHEAD * DHEAD);   // [dv][d]
#pragma unroll
  for (int tc = 0; tc < 8; ++tc)
#pragma unroll
    for (int r = 0; r < 4; ++r) {
      int dv = yv * 64 + wave * 16 + kgrp * 4 + r;
      int d = tc * 16 + lrow;
      KVout[dv * DHEAD + d] = acc[tc][r];
    }
  if (yv == 0) {
    int d = tid & 127, hh = tid >> 7;
    float s = 0.0f;
    for (int t = hh * 64; t < hh * 64 + 64; ++t) s += bf2f(kt[d][t]);
    csum[hh][d] = s;
    __syncthreads();
    if (tid < 128) ksc[(size_t)c * DHEAD + tid] = csum[0][tid] + csum[1][tid];
  }
}

// ---------------- K3: exclusive prefix over chunks ----------------
__global__ __launch_bounds__(256) void prefix_kernel(
    const float* __restrict__ KVc, const float* __restrict__ ksc,
    unsigned short* __restrict__ KVp, float* __restrict__ ksp) {
  if (blockIdx.x < 256) {
    int id = blockIdx.x * 256 + threadIdx.x;
    int b = id >> 14;
    int e = id & 16383;
    size_t base = (size_t)b * NCHUNK * 16384 + e;
    float acc = 0.0f;
    for (int c = 0; c < NCHUNK; ++c) {
      KVp[base + (size_t)c * 16384] = f2bf(acc);
      acc += KVc[base + (size_t)c * 16384];
    }
  } else {
    for (int i = threadIdx.x; i < 512; i += 256) {
      int b = i >> 7, d = i & 127;
      size_t base = (size_t)b * NCHUNK * DHEAD + d;
      float acc = 0.0f;
      for (int c = 0; c < NCHUNK; ++c) {
        ksp[base + (size_t)c * DHEAD] = acc;
        acc += ksc[base + (size_t)c * DHEAD];
      }
    }
  }
}

// ---------------- K4: per-chunk output, split in q-row halves ----------------
__global__ __launch_bounds__(256) void out_kernel(
    const unsigned short* __restrict__ phiQ, const unsigned short* __restrict__ phiK,
    const unsigned short* __restrict__ Vb, const unsigned short* __restrict__ KVp,
    const float* __restrict__ ksp, float* __restrict__ outp) {
  const int c = blockIdx.x;
  const int h = blockIdx.y;
  const size_t kvbase = (size_t)c * CHUNK * DHEAD;
  const size_t qbase = kvbase + (size_t)h * 64 * DHEAD;
  __shared__ unsigned short qb[64][136];
  __shared__ unsigned short kb[128][136];
  __shared__ unsigned short vt[128][136];
  __shared__ float dsum[4][64];
  __shared__ float ks_l[128];
  const int tid = threadIdx.x;
  const int wave = tid >> 6, lane = tid & 63;
  const int lrow = lane & 15, kgrp = lane >> 4;

#pragma unroll
  for (int it = 0; it < 4; ++it) {
    int idx = it * 256 + tid;
    int t = idx >> 4;
    int d0 = (idx & 15) << 3;
    *reinterpret_cast<uint4*>(&qb[t][d0]) =
        *reinterpret_cast<const uint4*>(&phiQ[qbase + (size_t)t * DHEAD + d0]);
  }
  if (tid < 128) ks_l[tid] = ksp[(size_t)c * DHEAD + tid];
  if (h == 0) {
#pragma unroll
    for (int it = 0; it < 4; ++it) {
      int idx = it * 256 + tid;
      int t = idx >> 4;
      int d0 = (idx & 15) << 3;
      *reinterpret_cast<uint4*>(&kb[t][d0]) =
          *reinterpret_cast<const uint4*>(&phiK[kvbase + (size_t)t * DHEAD + d0]);
    }
    int t = tid & 63, dp = tid >> 6;
#pragma unroll
    for (int i = 0; i < 4; ++i) {
      int d0 = (dp + 4 * i) * 8;
      uint4 v4 = *reinterpret_cast<const uint4*>(&Vb[kvbase + (size_t)t * DHEAD + d0]);
      const unsigned short* vp = reinterpret_cast<const unsigned short*>(&v4);
#pragma unroll
      for (int j = 0; j < 8; ++j) vt[d0 + j][t] = vp[j];
    }
  } else {
#pragma unroll
    for (int it = 0; it < 8; ++it) {
      int idx = it * 256 + tid;
      int t = idx >> 4;
      int d0 = (idx & 15) << 3;
      *reinterpret_cast<uint4*>(&kb[t][d0]) =
          *reinterpret_cast<const uint4*>(&phiK[kvbase + (size_t)t * DHEAD + d0]);
    }
    int t = tid & 127, dp = tid >> 7;
#pragma unroll
    for (int i = 0; i < 8; ++i) {
      int d0 = (dp + 2 * i) * 8;
      uint4 v4 = *reinterpret_cast<const uint4*>(&Vb[kvbase + (size_t)t * DHEAD + d0]);
      const unsigned short* vp = reinterpret_cast<const unsigned short*>(&v4);
#pragma unroll
      for (int j = 0; j < 8; ++j) vt[d0 + j][t] = vp[j];
    }
  }
  __syncthreads();

  if (h == 0) {
    f32x4 sa[4];
#pragma unroll
    for (int i = 0; i < 4; ++i) sa[i] = (f32x4)0.0f;
#pragma unroll
    for (int ks = 0; ks < 4; ++ks) {
      int d0 = ks * 32 + kgrp * 8;
      bf16x8 af = *reinterpret_cast<const bf16x8*>(&qb[wave * 16 + lrow][d0]);
#pragma unroll
      for (int tc = 0; tc < 4; ++tc) {
        bf16x8 bf = *reinterpret_cast<const bf16x8*>(&kb[tc * 16 + lrow][d0]);
        sa[tc] = __builtin_amdgcn_mfma_f32_16x16x32_bf16(af, bf, sa[tc], 0, 0, 0);
      }
    }
    __syncthreads();
#pragma unroll
    for (int tc = 0; tc < 4; ++tc)
#pragma unroll
      for (int r = 0; r < 4; ++r) {
        int trow = wave * 16 + kgrp * 4 + r;
        int s = tc * 16 + lrow;
        kb[trow][s] = f2bf((s <= trow) ? sa[tc][r] : 0.0f);
      }
  } else {
    f32x4 sa[8];
#pragma unroll
    for (int i = 0; i < 8; ++i) sa[i] = (f32x4)0.0f;
#pragma unroll
    for (int ks = 0; ks < 4; ++ks) {
      int d0 = ks * 32 + kgrp * 8;
      bf16x8 af = *reinterpret_cast<const bf16x8*>(&qb[wave * 16 + lrow][d0]);
#pragma unroll
      for (int tc = 0; tc < 8; ++tc) {
        bf16x8 bf = *reinterpret_cast<const bf16x8*>(&kb[tc * 16 + lrow][d0]);
        sa[tc] = __builtin_amdgcn_mfma_f32_16x16x32_bf16(af, bf, sa[tc], 0, 0, 0);
      }
    }
    __syncthreads();
#pragma unroll
    for (int tc = 0; tc < 8; ++tc)
#pragma unroll
      for (int r = 0; r < 4; ++r) {
        int trow = wave * 16 + kgrp * 4 + r;
        int s = tc * 16 + lrow;
        kb[trow][s] = f2bf((s <= 64 + trow) ? sa[tc][r] : 0.0f);
      }
  }
  __syncthreads();   // P visible

  {
    int t = tid & 63, h4 = tid >> 6;
    float s = 0.0f;
    if (h4 < 2) {
      if (h4 == 0 || h == 1) {
        for (int j = h4 * 64; j < h4 * 64 + 64; ++j) s += bf2f(kb[t][j]);
      }
    } else {
      for (int j = (h4 - 2) * 64; j < (h4 - 2) * 64 + 64; ++j)
        s += bf2f(qb[t][j]) * ks_l[j];
    }
    dsum[h4][t] = s;
  }

  f32x4 acc[8];
#pragma unroll
  for (int i = 0; i < 8; ++i) acc[i] = (f32x4)0.0f;
  {
    const int nks = (h == 0) ? 2 : 4;
    for (int ks = 0; ks < nks; ++ks) {
      int t0 = ks * 32 + kgrp * 8;
      bf16x8 af = *reinterpret_cast<const bf16x8*>(&kb[wave * 16 + lrow][t0]);
#pragma unroll
      for (int tc = 0; tc < 8; ++tc) {
        bf16x8 bf = *reinterpret_cast<const bf16x8*>(&vt[tc * 16 + lrow][t0]);
        acc[tc] = __builtin_amdgcn_mfma_f32_16x16x32_bf16(af, bf, acc[tc], 0, 0, 0);
      }
    }
  }
  __syncthreads();

#pragma unroll
  for (int it = 0; it < 8; ++it) {
    int idx = it * 256 + tid;
    int dv = idx >> 4;
    int d0 = (idx & 15) << 3;
    *reinterpret_cast<uint4*>(&vt[dv][d0]) =
        *reinterpret_cast<const uint4*>(&KVp[(size_t)c * 16384 + (size_t)dv * DHEAD + d0]);
  }
  __syncthreads();

#pragma unroll
  for (int ks = 0; ks < 4; ++ks) {
    int d0 = ks * 32 + kgrp * 8;
    bf16x8 af = *reinterpret_cast<const bf16x8*>(&qb[wave * 16 + lrow][d0]);
#pragma unroll
    for (int tc = 0; tc < 8; ++tc) {
      bf16x8 bf = *reinterpret_cast<const bf16x8*>(&vt[tc * 16 + lrow][d0]);
      acc[tc] = __builtin_amdgcn_mfma_f32_16x16x32_bf16(af, bf, acc[tc], 0, 0, 0);
    }
  }

#pragma unroll
  for (int tc = 0; tc < 8; ++tc)
#pragma unroll
    for (int r = 0; r < 4; ++r) {
      int trow = wave * 16 + kgrp * 4 + r;
      int dv = tc * 16 + lrow;
      float den = dsum[0][trow] + dsum[1][trow] + dsum[2][trow] + dsum[3][trow];
      outp[qbase + (size_t)trow * DHEAD + dv] = acc[tc][r] / den;
    }
}

extern "C" void kernel_launch(void* const* d_in, const int* in_sizes, int n_in,
                              void* d_out, int out_size, void* d_ws, size_t ws_size,
                              hipStream_t stream) {
  const float* x  = (const float*)d_in[0];
  const float* Wq = (const float*)d_in[1];
  const float* Wk = (const float*)d_in[2];
  const float* Wv = (const float*)d_in[3];
  float* out = (float*)d_out;
  char* ws = (char*)d_ws;
  unsigned short* phiQ = (unsigned short*)(ws + 0);          // 4 MB
  unsigned short* phiK = (unsigned short*)(ws + 4194304);    // 4 MB
  unsigned short* Vb   = (unsigned short*)(ws + 8388608);    // 4 MB
  unsigned short* WT   = (unsigned short*)(ws + 12582912);   // 768 KB
  float*          KVc  = (float*)(ws + 13369344);            // 8 MB
  unsigned short* KVp  = (unsigned short*)(ws + 21757952);   // 4 MB
  float*          ksc  = (float*)(ws + 25952256);            // 64 KB
  float*          ksp  = (float*)(ws + 26017792);            // 64 KB

  transpose_w_kernel<<<1536, 256, 0, stream>>>(Wq, Wk, Wv, WT);
  proj_kernel<<<1024, 256, 0, stream>>>(x, WT, phiQ, phiK, Vb);
  chunkkv_kernel<<<dim3(128, 2), 256, 0, stream>>>(phiK, Vb, KVc, ksc);
  prefix_kernel<<<257, 256, 0, stream>>>(KVc, ksc, KVp, ksp);
  out_kernel<<<dim3(128, 2), 256, 0, stream>>>(phiQ, phiK, Vb, KVp, ksp, out);
}

// Round 13
// 73.496 us; speedup vs baseline: 1.0893x; 1.0893x over previous
//
#include <hip/hip_runtime.h>

#define DMODEL 1024
#define DHEAD 128
#define CHUNK 128
#define NCHUNK 32

typedef __attribute__((ext_vector_type(4))) float f32x4;
typedef __attribute__((ext_vector_type(8))) short bf16x8;

__device__ __forceinline__ unsigned short f2bf(float f) {
  union { float f; unsigned u; } v; v.f = f;
  unsigned r = v.u + 0x7FFF + ((v.u >> 16) & 1);   // RNE
  return (unsigned short)(r >> 16);
}
__device__ __forceinline__ float bf2f(unsigned short h) {
  union { unsigned u; float f; } v; v.u = ((unsigned)h) << 16;
  return v.f;
}
__device__ __forceinline__ unsigned cvtpk(float lo, float hi) {
  unsigned r;
  asm("v_cvt_pk_bf16_f32 %0, %1, %2" : "=v"(r) : "v"(lo), "v"(hi));
  return r;
}
__device__ __forceinline__ void gload16(const void* g, void* l) {
  __builtin_amdgcn_global_load_lds(
      (const __attribute__((address_space(1))) unsigned int*)g,
      (__attribute__((address_space(3))) unsigned int*)l, 16, 0, 0);
}

// ---------------- K0: W -> W^T bf16 [which][n][k] ----------------
__global__ __launch_bounds__(256) void transpose_w_kernel(
    const float* __restrict__ Wq, const float* __restrict__ Wk,
    const float* __restrict__ Wv, unsigned short* __restrict__ WT) {
  int id = blockIdx.x * 256 + threadIdx.x;
  int w = id >> 17;
  int rem = id & 131071;
  int n = rem >> 10;
  int k = rem & 1023;
  const float* W = (w == 0) ? Wq : (w == 1) ? Wk : Wv;
  WT[id] = f2bf(W[(size_t)k * DHEAD + n]);
}

// ---------------- K1: projection GEMM + phi ----------------
// grid (256, 3): BM=64, BN=128, BK=128 (8 fat steps), 128 threads (2 waves).
// x: reg-staged fp32->bf16 into swizzled LDS (16 KB); W: gload16 (32 KB).
__global__ __launch_bounds__(128) void proj_kernel(
    const float* __restrict__ x, const unsigned short* __restrict__ WT,
    unsigned short* __restrict__ phiQ, unsigned short* __restrict__ phiK,
    unsigned short* __restrict__ Vb) {
  const int which = blockIdx.y;
  const unsigned short* Wt = WT + (size_t)which * (DHEAD * DMODEL);
  unsigned short* outp = (which == 0) ? phiQ : (which == 1) ? phiK : Vb;
  const int m0 = blockIdx.x * 64;

  __shared__ unsigned short xs[64][128];   // 16 KB bf16, 256B rows, swizzled
  __shared__ unsigned short ws[128][128];  // 32 KB bf16, 256B rows, swizzled

  const int tid = threadIdx.x;
  const int wave = tid >> 6;
  const int lane = tid & 63;
  const int lrow = lane & 15, kgrp = lane >> 4;

  f32x4 acc[2][8];
#pragma unroll
  for (int i = 0; i < 2; ++i)
#pragma unroll
    for (int j = 0; j < 8; ++j) acc[i][j] = (f32x4)0.0f;

  float4 xr[16];

#define LOADX(T)                                                           \
  {                                                                        \
    _Pragma("unroll")                                                      \
    for (int i = 0; i < 16; ++i) {                                         \
      int c = i * 128 + tid;        /* 2048 float4 chunks */               \
      int row = c >> 5;                                                    \
      int col4 = c & 31;                                                   \
      xr[i] = *reinterpret_cast<const float4*>(                            \
          &x[(size_t)(m0 + row) * DMODEL + (T) * 128 + col4 * 4]);         \
    }                                                                      \
  }
#define WRITEX()                                                           \
  {                                                                        \
    _Pragma("unroll")                                                      \
    for (int i = 0; i < 16; ++i) {                                         \
      int c = i * 128 + tid;                                               \
      int row = c >> 5;                                                    \
      int col4 = c & 31;                                                   \
      int sl = (col4 >> 1) ^ ((row & 7) << 1);                             \
      uint2 b;                                                             \
      b.x = cvtpk(xr[i].x, xr[i].y);                                       \
      b.y = cvtpk(xr[i].z, xr[i].w);                                       \
      *reinterpret_cast<uint2*>(                                           \
          (char*)&xs[row][0] + sl * 16 + (col4 & 1) * 8) = b;              \
    }                                                                      \
  }

  LOADX(0);
  for (int t = 0; t < 8; ++t) {
    if (t) __syncthreads();                // prior readers done
    // stage W tile 128x128 bf16 via gload16, source-swizzled
#pragma unroll
    for (int i = 0; i < 16; ++i) {
      int instr = i * 2 + wave;            // 32 wave-instrs of 1 KB
      int row = instr * 4 + (lane >> 4);
      int slotc = lane & 15;
      int sl = slotc ^ ((row & 7) << 1);
      gload16(&Wt[(size_t)row * DMODEL + t * 128 + sl * 8],
              (char*)ws + instr * 1024);
    }
    WRITEX();
    __syncthreads();                       // drain: W vmcnt + x lgkm
    if (t < 7) LOADX(t + 1);               // issue early; lands under compute
#pragma unroll
    for (int ks2 = 0; ks2 < 4; ++ks2) {
      bf16x8 af[2];
#pragma unroll
      for (int mi = 0; mi < 2; ++mi) {
        int arow = wave * 32 + mi * 16 + lrow;
        int sl = (ks2 * 4 + kgrp) ^ ((arow & 7) << 1);
        af[mi] = *reinterpret_cast<const bf16x8*>((char*)&xs[arow][0] + sl * 16);
      }
#pragma unroll
      for (int tc = 0; tc < 8; ++tc) {
        int brow = tc * 16 + lrow;
        int sl = (ks2 * 4 + kgrp) ^ ((brow & 7) << 1);
        bf16x8 bf = *reinterpret_cast<const bf16x8*>((char*)&ws[brow][0] + sl * 16);
        acc[0][tc] = __builtin_amdgcn_mfma_f32_16x16x32_bf16(af[0], bf, acc[0][tc], 0, 0, 0);
        acc[1][tc] = __builtin_amdgcn_mfma_f32_16x16x32_bf16(af[1], bf, acc[1][tc], 0, 0, 0);
      }
    }
  }
#undef LOADX
#undef WRITEX

  // epilogue: phi for q/k, plain for v; store bf16
#pragma unroll
  for (int mi = 0; mi < 2; ++mi)
#pragma unroll
    for (int tc = 0; tc < 8; ++tc)
#pragma unroll
      for (int r = 0; r < 4; ++r) {
        int row = m0 + wave * 32 + mi * 16 + kgrp * 4 + r;
        int col = tc * 16 + lrow;
        float v = acc[mi][tc][r];
        if (which < 2) v = (v > 0.0f) ? (v + 1.0f) : __expf(v);
        outp[(size_t)row * DHEAD + col] = f2bf(v);
      }
}

// ---------------- K2: per-chunk KV^T = v^T @ k (dv-split), ks colsums ----------------
__global__ __launch_bounds__(256) void chunkkv_kernel(
    const unsigned short* __restrict__ phiK, const unsigned short* __restrict__ Vb,
    float* __restrict__ KVc, float* __restrict__ ksc) {
  const int c = blockIdx.x;
  const int yv = blockIdx.y;
  const size_t base = (size_t)c * CHUNK * DHEAD;
  __shared__ unsigned short kt[128][136];   // k^T [d][t] (full)
  __shared__ unsigned short vt[64][136];    // v^T rows yv*64..+64
  __shared__ float csum[2][128];
  const int tid = threadIdx.x;
  const int wave = tid >> 6, lane = tid & 63;
  const int lrow = lane & 15, kgrp = lane >> 4;

  {
    int t = tid & 127, dp = tid >> 7;
#pragma unroll
    for (int i = 0; i < 8; ++i) {
      int d0 = (dp + 2 * i) * 8;
      uint4 k4 = *reinterpret_cast<const uint4*>(&phiK[base + (size_t)t * DHEAD + d0]);
      const unsigned short* kp = reinterpret_cast<const unsigned short*>(&k4);
#pragma unroll
      for (int j = 0; j < 8; ++j) kt[d0 + j][t] = kp[j];
    }
#pragma unroll
    for (int i = 0; i < 4; ++i) {
      int dl = (dp + 2 * i) * 8;             // 0..63 local dv
      uint4 v4 = *reinterpret_cast<const uint4*>(
          &Vb[base + (size_t)t * DHEAD + yv * 64 + dl]);
      const unsigned short* vp = reinterpret_cast<const unsigned short*>(&v4);
#pragma unroll
      for (int j = 0; j < 8; ++j) vt[dl + j][t] = vp[j];
    }
  }
  __syncthreads();

  f32x4 acc[8];
#pragma unroll
  for (int j = 0; j < 8; ++j) acc[j] = (f32x4)0.0f;
#pragma unroll
  for (int ks = 0; ks < 4; ++ks) {
    int t0 = ks * 32 + kgrp * 8;
    bf16x8 afrag = *reinterpret_cast<const bf16x8*>(&vt[wave * 16 + lrow][t0]);
#pragma unroll
    for (int tc = 0; tc < 8; ++tc) {
      bf16x8 bfrag = *reinterpret_cast<const bf16x8*>(&kt[tc * 16 + lrow][t0]);
      acc[tc] = __builtin_amdgcn_mfma_f32_16x16x32_bf16(afrag, bfrag, acc[tc], 0, 0, 0);
    }
  }
  float* KVout = KVc + (size_t)c * (DHEAD * DHEAD);   // [dv][d]
#pragma unroll
  for (int tc = 0; tc < 8; ++tc)
#pragma unroll
    for (int r = 0; r < 4; ++r) {
      int dv = yv * 64 + wave * 16 + kgrp * 4 + r;
      int d = tc * 16 + lrow;
      KVout[dv * DHEAD + d] = acc[tc][r];
    }
  if (yv == 0) {
    int d = tid & 127, hh = tid >> 7;
    float s = 0.0f;
    for (int t = hh * 64; t < hh * 64 + 64; ++t) s += bf2f(kt[d][t]);
    csum[hh][d] = s;
    __syncthreads();
    if (tid < 128) ksc[(size_t)c * DHEAD + tid] = csum[0][tid] + csum[1][tid];
  }
}

// ---------------- K3: exclusive prefix over chunks ----------------
__global__ __launch_bounds__(256) void prefix_kernel(
    const float* __restrict__ KVc, const float* __restrict__ ksc,
    unsigned short* __restrict__ KVp, float* __restrict__ ksp) {
  if (blockIdx.x < 256) {
    int id = blockIdx.x * 256 + threadIdx.x;
    int b = id >> 14;
    int e = id & 16383;
    size_t base = (size_t)b * NCHUNK * 16384 + e;
    float acc = 0.0f;
    for (int c = 0; c < NCHUNK; ++c) {
      KVp[base + (size_t)c * 16384] = f2bf(acc);
      acc += KVc[base + (size_t)c * 16384];
    }
  } else {
    for (int i = threadIdx.x; i < 512; i += 256) {
      int b = i >> 7, d = i & 127;
      size_t base = (size_t)b * NCHUNK * DHEAD + d;
      float acc = 0.0f;
      for (int c = 0; c < NCHUNK; ++c) {
        ksp[base + (size_t)c * DHEAD] = acc;
        acc += ksc[base + (size_t)c * DHEAD];
      }
    }
  }
}

// ---------------- K4: per-chunk output, split in q-row halves ----------------
__global__ __launch_bounds__(256) void out_kernel(
    const unsigned short* __restrict__ phiQ, const unsigned short* __restrict__ phiK,
    const unsigned short* __restrict__ Vb, const unsigned short* __restrict__ KVp,
    const float* __restrict__ ksp, float* __restrict__ outp) {
  const int c = blockIdx.x;
  const int h = blockIdx.y;
  const size_t kvbase = (size_t)c * CHUNK * DHEAD;
  const size_t qbase = kvbase + (size_t)h * 64 * DHEAD;
  __shared__ unsigned short qb[64][136];
  __shared__ unsigned short kb[128][136];
  __shared__ unsigned short vt[128][136];
  __shared__ float dsum[4][64];
  __shared__ float ks_l[128];
  const int tid = threadIdx.x;
  const int wave = tid >> 6, lane = tid & 63;
  const int lrow = lane & 15, kgrp = lane >> 4;

#pragma unroll
  for (int it = 0; it < 4; ++it) {
    int idx = it * 256 + tid;
    int t = idx >> 4;
    int d0 = (idx & 15) << 3;
    *reinterpret_cast<uint4*>(&qb[t][d0]) =
        *reinterpret_cast<const uint4*>(&phiQ[qbase + (size_t)t * DHEAD + d0]);
  }
  if (tid < 128) ks_l[tid] = ksp[(size_t)c * DHEAD + tid];
  if (h == 0) {
#pragma unroll
    for (int it = 0; it < 4; ++it) {
      int idx = it * 256 + tid;
      int t = idx >> 4;
      int d0 = (idx & 15) << 3;
      *reinterpret_cast<uint4*>(&kb[t][d0]) =
          *reinterpret_cast<const uint4*>(&phiK[kvbase + (size_t)t * DHEAD + d0]);
    }
    int t = tid & 63, dp = tid >> 6;
#pragma unroll
    for (int i = 0; i < 4; ++i) {
      int d0 = (dp + 4 * i) * 8;
      uint4 v4 = *reinterpret_cast<const uint4*>(&Vb[kvbase + (size_t)t * DHEAD + d0]);
      const unsigned short* vp = reinterpret_cast<const unsigned short*>(&v4);
#pragma unroll
      for (int j = 0; j < 8; ++j) vt[d0 + j][t] = vp[j];
    }
  } else {
#pragma unroll
    for (int it = 0; it < 8; ++it) {
      int idx = it * 256 + tid;
      int t = idx >> 4;
      int d0 = (idx & 15) << 3;
      *reinterpret_cast<uint4*>(&kb[t][d0]) =
          *reinterpret_cast<const uint4*>(&phiK[kvbase + (size_t)t * DHEAD + d0]);
    }
    int t = tid & 127, dp = tid >> 7;
#pragma unroll
    for (int i = 0; i < 8; ++i) {
      int d0 = (dp + 2 * i) * 8;
      uint4 v4 = *reinterpret_cast<const uint4*>(&Vb[kvbase + (size_t)t * DHEAD + d0]);
      const unsigned short* vp = reinterpret_cast<const unsigned short*>(&v4);
#pragma unroll
      for (int j = 0; j < 8; ++j) vt[d0 + j][t] = vp[j];
    }
  }
  __syncthreads();

  if (h == 0) {
    f32x4 sa[4];
#pragma unroll
    for (int i = 0; i < 4; ++i) sa[i] = (f32x4)0.0f;
#pragma unroll
    for (int ks = 0; ks < 4; ++ks) {
      int d0 = ks * 32 + kgrp * 8;
      bf16x8 af = *reinterpret_cast<const bf16x8*>(&qb[wave * 16 + lrow][d0]);
#pragma unroll
      for (int tc = 0; tc < 4; ++tc) {
        bf16x8 bf = *reinterpret_cast<const bf16x8*>(&kb[tc * 16 + lrow][d0]);
        sa[tc] = __builtin_amdgcn_mfma_f32_16x16x32_bf16(af, bf, sa[tc], 0, 0, 0);
      }
    }
    __syncthreads();
#pragma unroll
    for (int tc = 0; tc < 4; ++tc)
#pragma unroll
      for (int r = 0; r < 4; ++r) {
        int trow = wave * 16 + kgrp * 4 + r;
        int s = tc * 16 + lrow;
        kb[trow][s] = f2bf((s <= trow) ? sa[tc][r] : 0.0f);
      }
  } else {
    f32x4 sa[8];
#pragma unroll
    for (int i = 0; i < 8; ++i) sa[i] = (f32x4)0.0f;
#pragma unroll
    for (int ks = 0; ks < 4; ++ks) {
      int d0 = ks * 32 + kgrp * 8;
      bf16x8 af = *reinterpret_cast<const bf16x8*>(&qb[wave * 16 + lrow][d0]);
#pragma unroll
      for (int tc = 0; tc < 8; ++tc) {
        bf16x8 bf = *reinterpret_cast<const bf16x8*>(&kb[tc * 16 + lrow][d0]);
        sa[tc] = __builtin_amdgcn_mfma_f32_16x16x32_bf16(af, bf, sa[tc], 0, 0, 0);
      }
    }
    __syncthreads();
#pragma unroll
    for (int tc = 0; tc < 8; ++tc)
#pragma unroll
      for (int r = 0; r < 4; ++r) {
        int trow = wave * 16 + kgrp * 4 + r;
        int s = tc * 16 + lrow;
        kb[trow][s] = f2bf((s <= 64 + trow) ? sa[tc][r] : 0.0f);
      }
  }
  __syncthreads();   // P visible

  {
    int t = tid & 63, h4 = tid >> 6;
    float s = 0.0f;
    if (h4 < 2) {
      if (h4 == 0 || h == 1) {
        for (int j = h4 * 64; j < h4 * 64 + 64; ++j) s += bf2f(kb[t][j]);
      }
    } else {
      for (int j = (h4 - 2) * 64; j < (h4 - 2) * 64 + 64; ++j)
        s += bf2f(qb[t][j]) * ks_l[j];
    }
    dsum[h4][t] = s;
  }

  f32x4 acc[8];
#pragma unroll
  for (int i = 0; i < 8; ++i) acc[i] = (f32x4)0.0f;
  {
    const int nks = (h == 0) ? 2 : 4;
    for (int ks = 0; ks < nks; ++ks) {
      int t0 = ks * 32 + kgrp * 8;
      bf16x8 af = *reinterpret_cast<const bf16x8*>(&kb[wave * 16 + lrow][t0]);
#pragma unroll
      for (int tc = 0; tc < 8; ++tc) {
        bf16x8 bf = *reinterpret_cast<const bf16x8*>(&vt[tc * 16 + lrow][t0]);
        acc[tc] = __builtin_amdgcn_mfma_f32_16x16x32_bf16(af, bf, acc[tc], 0, 0, 0);
      }
    }
  }
  __syncthreads();

#pragma unroll
  for (int it = 0; it < 8; ++it) {
    int idx = it * 256 + tid;
    int dv = idx >> 4;
    int d0 = (idx & 15) << 3;
    *reinterpret_cast<uint4*>(&vt[dv][d0]) =
        *reinterpret_cast<const uint4*>(&KVp[(size_t)c * 16384 + (size_t)dv * DHEAD + d0]);
  }
  __syncthreads();

#pragma unroll
  for (int ks = 0; ks < 4; ++ks) {
    int d0 = ks * 32 + kgrp * 8;
    bf16x8 af = *reinterpret_cast<const bf16x8*>(&qb[wave * 16 + lrow][d0]);
#pragma unroll
    for (int tc = 0; tc < 8; ++tc) {
      bf16x8 bf = *reinterpret_cast<const bf16x8*>(&vt[tc * 16 + lrow][d0]);
      acc[tc] = __builtin_amdgcn_mfma_f32_16x16x32_bf16(af, bf, acc[tc], 0, 0, 0);
    }
  }

#pragma unroll
  for (int tc = 0; tc < 8; ++tc)
#pragma unroll
    for (int r = 0; r < 4; ++r) {
      int trow = wave * 16 + kgrp * 4 + r;
      int dv = tc * 16 + lrow;
      float den = dsum[0][trow] + dsum[1][trow] + dsum[2][trow] + dsum[3][trow];
      outp[qbase + (size_t)trow * DHEAD + dv] = acc[tc][r] / den;
    }
}

extern "C" void kernel_launch(void* const* d_in, const int* in_sizes, int n_in,
                              void* d_out, int out_size, void* d_ws, size_t ws_size,
                              hipStream_t stream) {
  const float* x  = (const float*)d_in[0];
  const float* Wq = (const float*)d_in[1];
  const float* Wk = (const float*)d_in[2];
  const float* Wv = (const float*)d_in[3];
  float* out = (float*)d_out;
  char* ws = (char*)d_ws;
  unsigned short* phiQ = (unsigned short*)(ws + 0);          // 4 MB
  unsigned short* phiK = (unsigned short*)(ws + 4194304);    // 4 MB
  unsigned short* Vb   = (unsigned short*)(ws + 8388608);    // 4 MB
  unsigned short* WT   = (unsigned short*)(ws + 12582912);   // 768 KB
  float*          KVc  = (float*)(ws + 13369344);            // 8 MB
  unsigned short* KVp  = (unsigned short*)(ws + 21757952);   // 4 MB
  float*          ksc  = (float*)(ws + 25952256);            // 64 KB
  float*          ksp  = (float*)(ws + 26017792);            // 64 KB

  transpose_w_kernel<<<1536, 256, 0, stream>>>(Wq, Wk, Wv, WT);
  proj_kernel<<<dim3(256, 3), 128, 0, stream>>>(x, WT, phiQ, phiK, Vb);
  chunkkv_kernel<<<dim3(128, 2), 256, 0, stream>>>(phiK, Vb, KVc, ksc);
  prefix_kernel<<<257, 256, 0, stream>>>(KVc, ksc, KVp, ksp);
  out_kernel<<<dim3(128, 2), 256, 0, stream>>>(phiQ, phiK, Vb, KVp, ksp, out);
}

// Round 14
// 60.990 us; speedup vs baseline: 1.3127x; 1.2050x over previous
//
#include <hip/hip_runtime.h>

#define DMODEL 1024
#define DHEAD 128
#define CHUNK 128
#define NCHUNK 32

typedef __attribute__((ext_vector_type(4))) float f32x4;
typedef __attribute__((ext_vector_type(8))) short bf16x8;

__device__ __forceinline__ unsigned short f2bf(float f) {
  union { float f; unsigned u; } v; v.f = f;
  unsigned r = v.u + 0x7FFF + ((v.u >> 16) & 1);   // RNE
  return (unsigned short)(r >> 16);
}
__device__ __forceinline__ float bf2f(unsigned short h) {
  union { unsigned u; float f; } v; v.u = ((unsigned)h) << 16;
  return v.f;
}
__device__ __forceinline__ unsigned cvtpk(float lo, float hi) {
  unsigned r;
  asm("v_cvt_pk_bf16_f32 %0, %1, %2" : "=v"(r) : "v"(lo), "v"(hi));
  return r;
}
__device__ __forceinline__ void gload16(const void* g, void* l) {
  __builtin_amdgcn_global_load_lds(
      (const __attribute__((address_space(1))) unsigned int*)g,
      (__attribute__((address_space(3))) unsigned int*)l, 16, 0, 0);
}

// ---------------- K0: W -> W^T bf16 [which][n][k] ----------------
__global__ __launch_bounds__(256) void transpose_w_kernel(
    const float* __restrict__ Wq, const float* __restrict__ Wk,
    const float* __restrict__ Wv, unsigned short* __restrict__ WT) {
  int id = blockIdx.x * 256 + threadIdx.x;
  int w = id >> 17;
  int rem = id & 131071;
  int n = rem >> 10;
  int k = rem & 1023;
  const float* W = (w == 0) ? Wq : (w == 1) ? Wk : Wv;
  WT[id] = f2bf(W[(size_t)k * DHEAD + n]);
}

// ---------------- K1: FUSED projection + phi, A-direct ----------------
// grid 512: BM=64 (wave strip 16 rows), BN=64 (n-half), BK=128, 256 threads.
// x (A-operand): per-lane float4 global loads, no LDS. W: gload16 into 48 KB LDS.
__global__ __launch_bounds__(256) void proj_kernel(
    const float* __restrict__ x, const unsigned short* __restrict__ WT,
    unsigned short* __restrict__ phiQ, unsigned short* __restrict__ phiK,
    unsigned short* __restrict__ Vb) {
  const int bid = blockIdx.x;
  // pair (bid, bid+8) = two n-halves of same m-tile, same XCD residue
  const int nh = (bid >> 3) & 1;
  const int mt = (bid & 7) + ((bid >> 4) << 3);   // 0..255
  const int n0 = nh << 6;
  const int m0 = mt << 6;

  __shared__ unsigned short wl[3][64][128];   // 48 KB, 256B rows = 16 slots, swizzled

  const int tid = threadIdx.x;
  const int wave = tid >> 6;
  const int lane = tid & 63;
  const int lrow = lane & 15, kgrp = lane >> 4;

  const float* xrow = &x[(size_t)(m0 + wave * 16 + lrow) * DMODEL + kgrp * 8];

  f32x4 acc[3][4];
#pragma unroll
  for (int w3 = 0; w3 < 3; ++w3)
#pragma unroll
    for (int nt = 0; nt < 4; ++nt) acc[w3][nt] = (f32x4)0.0f;

  for (int t = 0; t < 8; ++t) {
    if (t) __syncthreads();                 // readers done before overwrite
    // stage W slab [3][64 rows][BK=128] bf16: 48 instrs of 1 KB, source-swizzled
#pragma unroll
    for (int i = 0; i < 12; ++i) {
      int instr = i * 4 + wave;             // 0..47
      int w3 = instr >> 4;
      int rowblk = instr & 15;
      int row = rowblk * 4 + (lane >> 4);
      int slot = lane & 15;
      int gcol = (slot ^ ((row & 7) << 1)) << 3;
      gload16(&WT[(size_t)w3 * (DHEAD * DMODEL) + (size_t)(n0 + row) * DMODEL + t * 128 + gcol],
              (char*)wl + instr * 1024);
    }
    // x A-fragments for this step (per-lane, 128B/row segments)
    float4 xa[8];
#pragma unroll
    for (int ks = 0; ks < 4; ++ks) {
      xa[2 * ks]     = *reinterpret_cast<const float4*>(xrow + t * 128 + ks * 32);
      xa[2 * ks + 1] = *reinterpret_cast<const float4*>(xrow + t * 128 + ks * 32 + 4);
    }
    __syncthreads();                        // drains W (and x already by use)

#pragma unroll
    for (int ks = 0; ks < 4; ++ks) {
      union { unsigned u[4]; bf16x8 v; } p;
      p.u[0] = cvtpk(xa[2 * ks].x, xa[2 * ks].y);
      p.u[1] = cvtpk(xa[2 * ks].z, xa[2 * ks].w);
      p.u[2] = cvtpk(xa[2 * ks + 1].x, xa[2 * ks + 1].y);
      p.u[3] = cvtpk(xa[2 * ks + 1].z, xa[2 * ks + 1].w);
      bf16x8 af = p.v;
      int s = ks * 4 + kgrp;
#pragma unroll
      for (int w3 = 0; w3 < 3; ++w3)
#pragma unroll
        for (int nt = 0; nt < 4; ++nt) {
          int brow = nt * 16 + lrow;
          int sl = s ^ ((brow & 7) << 1);
          bf16x8 bf = *reinterpret_cast<const bf16x8*>(
              (char*)wl + w3 * 16384 + brow * 256 + sl * 16);
          acc[w3][nt] = __builtin_amdgcn_mfma_f32_16x16x32_bf16(af, bf, acc[w3][nt], 0, 0, 0);
        }
    }
  }

  // epilogue: phi for q/k, plain for v; store bf16
#pragma unroll
  for (int w3 = 0; w3 < 3; ++w3) {
    unsigned short* outp = (w3 == 0) ? phiQ : (w3 == 1) ? phiK : Vb;
#pragma unroll
    for (int nt = 0; nt < 4; ++nt)
#pragma unroll
      for (int r = 0; r < 4; ++r) {
        int row = m0 + wave * 16 + kgrp * 4 + r;
        int col = n0 + nt * 16 + lrow;
        float v = acc[w3][nt][r];
        if (w3 < 2) v = (v > 0.0f) ? (v + 1.0f) : __expf(v);
        outp[(size_t)row * DHEAD + col] = f2bf(v);
      }
  }
}

// ---------------- K2: per-chunk KV^T = v^T @ k (dv-split), ks colsums ----------------
__global__ __launch_bounds__(256) void chunkkv_kernel(
    const unsigned short* __restrict__ phiK, const unsigned short* __restrict__ Vb,
    float* __restrict__ KVc, float* __restrict__ ksc) {
  const int c = blockIdx.x;
  const int yv = blockIdx.y;
  const size_t base = (size_t)c * CHUNK * DHEAD;
  __shared__ unsigned short kt[128][136];   // k^T [d][t] (full)
  __shared__ unsigned short vt[64][136];    // v^T rows yv*64..+64
  __shared__ float csum[2][128];
  const int tid = threadIdx.x;
  const int wave = tid >> 6, lane = tid & 63;
  const int lrow = lane & 15, kgrp = lane >> 4;

  {
    int t = tid & 127, dp = tid >> 7;
#pragma unroll
    for (int i = 0; i < 8; ++i) {
      int d0 = (dp + 2 * i) * 8;
      uint4 k4 = *reinterpret_cast<const uint4*>(&phiK[base + (size_t)t * DHEAD + d0]);
      const unsigned short* kp = reinterpret_cast<const unsigned short*>(&k4);
#pragma unroll
      for (int j = 0; j < 8; ++j) kt[d0 + j][t] = kp[j];
    }
#pragma unroll
    for (int i = 0; i < 4; ++i) {
      int dl = (dp + 2 * i) * 8;             // 0..63 local dv
      uint4 v4 = *reinterpret_cast<const uint4*>(
          &Vb[base + (size_t)t * DHEAD + yv * 64 + dl]);
      const unsigned short* vp = reinterpret_cast<const unsigned short*>(&v4);
#pragma unroll
      for (int j = 0; j < 8; ++j) vt[dl + j][t] = vp[j];
    }
  }
  __syncthreads();

  f32x4 acc[8];
#pragma unroll
  for (int j = 0; j < 8; ++j) acc[j] = (f32x4)0.0f;
#pragma unroll
  for (int ks = 0; ks < 4; ++ks) {
    int t0 = ks * 32 + kgrp * 8;
    bf16x8 afrag = *reinterpret_cast<const bf16x8*>(&vt[wave * 16 + lrow][t0]);
#pragma unroll
    for (int tc = 0; tc < 8; ++tc) {
      bf16x8 bfrag = *reinterpret_cast<const bf16x8*>(&kt[tc * 16 + lrow][t0]);
      acc[tc] = __builtin_amdgcn_mfma_f32_16x16x32_bf16(afrag, bfrag, acc[tc], 0, 0, 0);
    }
  }
  float* KVout = KVc + (size_t)c * (DHEAD * DHEAD);   // [dv][d]
#pragma unroll
  for (int tc = 0; tc < 8; ++tc)
#pragma unroll
    for (int r = 0; r < 4; ++r) {
      int dv = yv * 64 + wave * 16 + kgrp * 4 + r;
      int d = tc * 16 + lrow;
      KVout[dv * DHEAD + d] = acc[tc][r];
    }
  if (yv == 0) {
    int d = tid & 127, hh = tid >> 7;
    float s = 0.0f;
    for (int t = hh * 64; t < hh * 64 + 64; ++t) s += bf2f(kt[d][t]);
    csum[hh][d] = s;
    __syncthreads();
    if (tid < 128) ksc[(size_t)c * DHEAD + tid] = csum[0][tid] + csum[1][tid];
  }
}

// ---------------- K3: exclusive prefix over chunks ----------------
__global__ __launch_bounds__(256) void prefix_kernel(
    const float* __restrict__ KVc, const float* __restrict__ ksc,
    unsigned short* __restrict__ KVp, float* __restrict__ ksp) {
  if (blockIdx.x < 256) {
    int id = blockIdx.x * 256 + threadIdx.x;
    int b = id >> 14;
    int e = id & 16383;
    size_t base = (size_t)b * NCHUNK * 16384 + e;
    float acc = 0.0f;
    for (int c = 0; c < NCHUNK; ++c) {
      KVp[base + (size_t)c * 16384] = f2bf(acc);
      acc += KVc[base + (size_t)c * 16384];
    }
  } else {
    for (int i = threadIdx.x; i < 512; i += 256) {
      int b = i >> 7, d = i & 127;
      size_t base = (size_t)b * NCHUNK * DHEAD + d;
      float acc = 0.0f;
      for (int c = 0; c < NCHUNK; ++c) {
        ksp[base + (size_t)c * DHEAD] = acc;
        acc += ksc[base + (size_t)c * DHEAD];
      }
    }
  }
}

// ---------------- K4: per-chunk output, split in q-row halves ----------------
__global__ __launch_bounds__(256) void out_kernel(
    const unsigned short* __restrict__ phiQ, const unsigned short* __restrict__ phiK,
    const unsigned short* __restrict__ Vb, const unsigned short* __restrict__ KVp,
    const float* __restrict__ ksp, float* __restrict__ outp) {
  const int c = blockIdx.x;
  const int h = blockIdx.y;
  const size_t kvbase = (size_t)c * CHUNK * DHEAD;
  const size_t qbase = kvbase + (size_t)h * 64 * DHEAD;
  __shared__ unsigned short qb[64][136];
  __shared__ unsigned short kb[128][136];
  __shared__ unsigned short vt[128][136];
  __shared__ float dsum[4][64];
  __shared__ float ks_l[128];
  const int tid = threadIdx.x;
  const int wave = tid >> 6, lane = tid & 63;
  const int lrow = lane & 15, kgrp = lane >> 4;

#pragma unroll
  for (int it = 0; it < 4; ++it) {
    int idx = it * 256 + tid;
    int t = idx >> 4;
    int d0 = (idx & 15) << 3;
    *reinterpret_cast<uint4*>(&qb[t][d0]) =
        *reinterpret_cast<const uint4*>(&phiQ[qbase + (size_t)t * DHEAD + d0]);
  }
  if (tid < 128) ks_l[tid] = ksp[(size_t)c * DHEAD + tid];
  if (h == 0) {
#pragma unroll
    for (int it = 0; it < 4; ++it) {
      int idx = it * 256 + tid;
      int t = idx >> 4;
      int d0 = (idx & 15) << 3;
      *reinterpret_cast<uint4*>(&kb[t][d0]) =
          *reinterpret_cast<const uint4*>(&phiK[kvbase + (size_t)t * DHEAD + d0]);
    }
    int t = tid & 63, dp = tid >> 6;
#pragma unroll
    for (int i = 0; i < 4; ++i) {
      int d0 = (dp + 4 * i) * 8;
      uint4 v4 = *reinterpret_cast<const uint4*>(&Vb[kvbase + (size_t)t * DHEAD + d0]);
      const unsigned short* vp = reinterpret_cast<const unsigned short*>(&v4);
#pragma unroll
      for (int j = 0; j < 8; ++j) vt[d0 + j][t] = vp[j];
    }
  } else {
#pragma unroll
    for (int it = 0; it < 8; ++it) {
      int idx = it * 256 + tid;
      int t = idx >> 4;
      int d0 = (idx & 15) << 3;
      *reinterpret_cast<uint4*>(&kb[t][d0]) =
          *reinterpret_cast<const uint4*>(&phiK[kvbase + (size_t)t * DHEAD + d0]);
    }
    int t = tid & 127, dp = tid >> 7;
#pragma unroll
    for (int i = 0; i < 8; ++i) {
      int d0 = (dp + 2 * i) * 8;
      uint4 v4 = *reinterpret_cast<const uint4*>(&Vb[kvbase + (size_t)t * DHEAD + d0]);
      const unsigned short* vp = reinterpret_cast<const unsigned short*>(&v4);
#pragma unroll
      for (int j = 0; j < 8; ++j) vt[d0 + j][t] = vp[j];
    }
  }
  __syncthreads();

  if (h == 0) {
    f32x4 sa[4];
#pragma unroll
    for (int i = 0; i < 4; ++i) sa[i] = (f32x4)0.0f;
#pragma unroll
    for (int ks = 0; ks < 4; ++ks) {
      int d0 = ks * 32 + kgrp * 8;
      bf16x8 af = *reinterpret_cast<const bf16x8*>(&qb[wave * 16 + lrow][d0]);
#pragma unroll
      for (int tc = 0; tc < 4; ++tc) {
        bf16x8 bf = *reinterpret_cast<const bf16x8*>(&kb[tc * 16 + lrow][d0]);
        sa[tc] = __builtin_amdgcn_mfma_f32_16x16x32_bf16(af, bf, sa[tc], 0, 0, 0);
      }
    }
    __syncthreads();
#pragma unroll
    for (int tc = 0; tc < 4; ++tc)
#pragma unroll
      for (int r = 0; r < 4; ++r) {
        int trow = wave * 16 + kgrp * 4 + r;
        int s = tc * 16 + lrow;
        kb[trow][s] = f2bf((s <= trow) ? sa[tc][r] : 0.0f);
      }
  } else {
    f32x4 sa[8];
#pragma unroll
    for (int i = 0; i < 8; ++i) sa[i] = (f32x4)0.0f;
#pragma unroll
    for (int ks = 0; ks < 4; ++ks) {
      int d0 = ks * 32 + kgrp * 8;
      bf16x8 af = *reinterpret_cast<const bf16x8*>(&qb[wave * 16 + lrow][d0]);
#pragma unroll
      for (int tc = 0; tc < 8; ++tc) {
        bf16x8 bf = *reinterpret_cast<const bf16x8*>(&kb[tc * 16 + lrow][d0]);
        sa[tc] = __builtin_amdgcn_mfma_f32_16x16x32_bf16(af, bf, sa[tc], 0, 0, 0);
      }
    }
    __syncthreads();
#pragma unroll
    for (int tc = 0; tc < 8; ++tc)
#pragma unroll
      for (int r = 0; r < 4; ++r) {
        int trow = wave * 16 + kgrp * 4 + r;
        int s = tc * 16 + lrow;
        kb[trow][s] = f2bf((s <= 64 + trow) ? sa[tc][r] : 0.0f);
      }
  }
  __syncthreads();   // P visible

  {
    int t = tid & 63, h4 = tid >> 6;
    float s = 0.0f;
    if (h4 < 2) {
      if (h4 == 0 || h == 1) {
        for (int j = h4 * 64; j < h4 * 64 + 64; ++j) s += bf2f(kb[t][j]);
      }
    } else {
      for (int j = (h4 - 2) * 64; j < (h4 - 2) * 64 + 64; ++j)
        s += bf2f(qb[t][j]) * ks_l[j];
    }
    dsum[h4][t] = s;
  }

  f32x4 acc[8];
#pragma unroll
  for (int i = 0; i < 8; ++i) acc[i] = (f32x4)0.0f;
  {
    const int nks = (h == 0) ? 2 : 4;
    for (int ks = 0; ks < nks; ++ks) {
      int t0 = ks * 32 + kgrp * 8;
      bf16x8 af = *reinterpret_cast<const bf16x8*>(&kb[wave * 16 + lrow][t0]);
#pragma unroll
      for (int tc = 0; tc < 8; ++tc) {
        bf16x8 bf = *reinterpret_cast<const bf16x8*>(&vt[tc * 16 + lrow][t0]);
        acc[tc] = __builtin_amdgcn_mfma_f32_16x16x32_bf16(af, bf, acc[tc], 0, 0, 0);
      }
    }
  }
  __syncthreads();

#pragma unroll
  for (int it = 0; it < 8; ++it) {
    int idx = it * 256 + tid;
    int dv = idx >> 4;
    int d0 = (idx & 15) << 3;
    *reinterpret_cast<uint4*>(&vt[dv][d0]) =
        *reinterpret_cast<const uint4*>(&KVp[(size_t)c * 16384 + (size_t)dv * DHEAD + d0]);
  }
  __syncthreads();

#pragma unroll
  for (int ks = 0; ks < 4; ++ks) {
    int d0 = ks * 32 + kgrp * 8;
    bf16x8 af = *reinterpret_cast<const bf16x8*>(&qb[wave * 16 + lrow][d0]);
#pragma unroll
    for (int tc = 0; tc < 8; ++tc) {
      bf16x8 bf = *reinterpret_cast<const bf16x8*>(&vt[tc * 16 + lrow][d0]);
      acc[tc] = __builtin_amdgcn_mfma_f32_16x16x32_bf16(af, bf, acc[tc], 0, 0, 0);
    }
  }

#pragma unroll
  for (int tc = 0; tc < 8; ++tc)
#pragma unroll
    for (int r = 0; r < 4; ++r) {
      int trow = wave * 16 + kgrp * 4 + r;
      int dv = tc * 16 + lrow;
      float den = dsum[0][trow] + dsum[1][trow] + dsum[2][trow] + dsum[3][trow];
      outp[qbase + (size_t)trow * DHEAD + dv] = acc[tc][r] / den;
    }
}

extern "C" void kernel_launch(void* const* d_in, const int* in_sizes, int n_in,
                              void* d_out, int out_size, void* d_ws, size_t ws_size,
                              hipStream_t stream) {
  const float* x  = (const float*)d_in[0];
  const float* Wq = (const float*)d_in[1];
  const float* Wk = (const float*)d_in[2];
  const float* Wv = (const float*)d_in[3];
  float* out = (float*)d_out;
  char* ws = (char*)d_ws;
  unsigned short* phiQ = (unsigned short*)(ws + 0);          // 4 MB
  unsigned short* phiK = (unsigned short*)(ws + 4194304);    // 4 MB
  unsigned short* Vb   = (unsigned short*)(ws + 8388608);    // 4 MB
  unsigned short* WT   = (unsigned short*)(ws + 12582912);   // 768 KB
  float*          KVc  = (float*)(ws + 13369344);            // 8 MB
  unsigned short* KVp  = (unsigned short*)(ws + 21757952);   // 4 MB
  float*          ksc  = (float*)(ws + 25952256);            // 64 KB
  float*          ksp  = (float*)(ws + 26017792);            // 64 KB

  transpose_w_kernel<<<1536, 256, 0, stream>>>(Wq, Wk, Wv, WT);
  proj_kernel<<<512, 256, 0, stream>>>(x, WT, phiQ, phiK, Vb);
  chunkkv_kernel<<<dim3(128, 2), 256, 0, stream>>>(phiK, Vb, KVc, ksc);
  prefix_kernel<<<257, 256, 0, stream>>>(KVc, ksc, KVp, ksp);
  out_kernel<<<dim3(128, 2), 256, 0, stream>>>(phiQ, phiK, Vb, KVp, ksp, out);
}

// Round 15
// 55.005 us; speedup vs baseline: 1.4555x; 1.1088x over previous
//
#include <hip/hip_runtime.h>

#define DMODEL 1024
#define DHEAD 128
#define CHUNK 128
#define NCHUNK 32

typedef __attribute__((ext_vector_type(4))) float f32x4;
typedef __attribute__((ext_vector_type(8))) short bf16x8;

__device__ __forceinline__ unsigned short f2bf(float f) {
  union { float f; unsigned u; } v; v.f = f;
  unsigned r = v.u + 0x7FFF + ((v.u >> 16) & 1);   // RNE
  return (unsigned short)(r >> 16);
}
__device__ __forceinline__ float bf2f(unsigned short h) {
  union { unsigned u; float f; } v; v.u = ((unsigned)h) << 16;
  return v.f;
}
__device__ __forceinline__ unsigned cvtpk(float lo, float hi) {
  unsigned r;
  asm("v_cvt_pk_bf16_f32 %0, %1, %2" : "=v"(r) : "v"(lo), "v"(hi));
  return r;
}
__device__ __forceinline__ void gload16(const void* g, void* l) {
  __builtin_amdgcn_global_load_lds(
      (const __attribute__((address_space(1))) unsigned int*)g,
      (__attribute__((address_space(3))) unsigned int*)l, 16, 0, 0);
}

// ---------------- K0: W -> W^T bf16 [which][n][k] ----------------
__global__ __launch_bounds__(256) void transpose_w_kernel(
    const float* __restrict__ Wq, const float* __restrict__ Wk,
    const float* __restrict__ Wv, unsigned short* __restrict__ WT) {
  int id = blockIdx.x * 256 + threadIdx.x;
  int w = id >> 17;
  int rem = id & 131071;
  int n = rem >> 10;
  int k = rem & 1023;
  const float* W = (w == 0) ? Wq : (w == 1) ? Wk : Wv;
  WT[id] = f2bf(W[(size_t)k * DHEAD + n]);
}

// ---------------- K1: FUSED projection + phi, 2-deep prefetch ----------------
// grid 512: BM=64 (wave = 16-row strip, 1 row/lane), BN=64 (n-half), BK=64.
// W: LDS double-buffer (2x24 KB) via gload16. x: direct-to-reg, va/vb sets.
__global__ __launch_bounds__(256) void proj_kernel(
    const float* __restrict__ x, const unsigned short* __restrict__ WT,
    unsigned short* __restrict__ phiQ, unsigned short* __restrict__ phiK,
    unsigned short* __restrict__ Vb) {
  const int bid = blockIdx.x;
  // pair (bid, bid+8) = two n-halves of same m-tile, same XCD residue
  const int nh = (bid >> 3) & 1;
  const int mt = (bid & 7) + ((bid >> 4) << 3);   // 0..255
  const int n0 = nh << 6;
  const int m0 = mt << 6;

  __shared__ unsigned short wl[2][3][64][64];   // 48 KB, 128B rows = 8 slots, swizzled

  const int tid = threadIdx.x;
  const int wave = tid >> 6;
  const int lane = tid & 63;
  const int lrow = lane & 15, kgrp = lane >> 4;

  const float* xrow = &x[(size_t)(m0 + wave * 16 + lrow) * DMODEL + kgrp * 8];

  f32x4 acc[3][4];
#pragma unroll
  for (int w3 = 0; w3 < 3; ++w3)
#pragma unroll
    for (int nt = 0; nt < 4; ++nt) acc[w3][nt] = (f32x4)0.0f;

  float4 va[4], vb[4];

#define WSTAGE(T, B)                                                        \
  {                                                                         \
    _Pragma("unroll")                                                       \
    for (int i = 0; i < 6; ++i) {                                           \
      int instr = i * 4 + wave;            /* 0..23, 1 KB each */           \
      int w3 = instr >> 3;                                                  \
      int jj = instr & 7;                                                   \
      int row = jj * 8 + (lane >> 3);                                       \
      int slot = lane & 7;                                                  \
      int gcol = (slot ^ (row & 7)) << 3;                                   \
      gload16(&WT[(size_t)w3 * (DHEAD * DMODEL) +                           \
                  (size_t)(n0 + row) * DMODEL + (T) * 64 + gcol],           \
              (char*)wl + (B) * 24576 + instr * 1024);                      \
    }                                                                       \
  }
#define XLOAD(T, V)                                                         \
  {                                                                         \
    _Pragma("unroll")                                                       \
    for (int ks = 0; ks < 2; ++ks) {                                        \
      V[2 * ks]     = *reinterpret_cast<const float4*>(xrow + (T) * 64 + ks * 32);     \
      V[2 * ks + 1] = *reinterpret_cast<const float4*>(xrow + (T) * 64 + ks * 32 + 4); \
    }                                                                       \
  }
#define COMPUTE(V, B)                                                       \
  {                                                                         \
    _Pragma("unroll")                                                       \
    for (int ks2 = 0; ks2 < 2; ++ks2) {                                     \
      union { unsigned u[4]; bf16x8 v; } p;                                 \
      p.u[0] = cvtpk(V[2 * ks2].x, V[2 * ks2].y);                           \
      p.u[1] = cvtpk(V[2 * ks2].z, V[2 * ks2].w);                           \
      p.u[2] = cvtpk(V[2 * ks2 + 1].x, V[2 * ks2 + 1].y);                   \
      p.u[3] = cvtpk(V[2 * ks2 + 1].z, V[2 * ks2 + 1].w);                   \
      bf16x8 af = p.v;                                                      \
      _Pragma("unroll")                                                     \
      for (int w3 = 0; w3 < 3; ++w3)                                        \
        _Pragma("unroll")                                                   \
        for (int nt = 0; nt < 4; ++nt) {                                    \
          int brow = nt * 16 + lrow;                                        \
          int sl = (ks2 * 4 + kgrp) ^ (brow & 7);                           \
          bf16x8 bf = *reinterpret_cast<const bf16x8*>(                     \
              (char*)wl + (B) * 24576 + w3 * 8192 + brow * 128 + sl * 16);  \
          acc[w3][nt] = __builtin_amdgcn_mfma_f32_16x16x32_bf16(            \
              af, bf, acc[w3][nt], 0, 0, 0);                                \
        }                                                                   \
    }                                                                       \
  }

  WSTAGE(0, 0);
  XLOAD(0, va);
  __syncthreads();                          // buffer 0 + va ready

#pragma unroll
  for (int tt = 0; tt < 8; ++tt) {
    const int t = tt * 2;
    // even step t: consume va, buffer 0-parity
    if (t + 1 < 16) { WSTAGE(t + 1, 1); XLOAD(t + 1, vb); }
    COMPUTE(va, 0);
    __syncthreads();
    // odd step t+1: consume vb, buffer 1-parity
    if (t + 2 < 16) { WSTAGE(t + 2, 0); XLOAD(t + 2, va); }
    COMPUTE(vb, 1);
    __syncthreads();
  }
#undef WSTAGE
#undef XLOAD
#undef COMPUTE

  // epilogue: phi for q/k, plain for v; store bf16
#pragma unroll
  for (int w3 = 0; w3 < 3; ++w3) {
    unsigned short* outp = (w3 == 0) ? phiQ : (w3 == 1) ? phiK : Vb;
#pragma unroll
    for (int nt = 0; nt < 4; ++nt)
#pragma unroll
      for (int r = 0; r < 4; ++r) {
        int row = m0 + wave * 16 + kgrp * 4 + r;
        int col = n0 + nt * 16 + lrow;
        float v = acc[w3][nt][r];
        if (w3 < 2) v = (v > 0.0f) ? (v + 1.0f) : __expf(v);
        outp[(size_t)row * DHEAD + col] = f2bf(v);
      }
  }
}

// ---------------- K2: per-chunk KV^T = v^T @ k (dv-split), ks colsums ----------------
__global__ __launch_bounds__(256) void chunkkv_kernel(
    const unsigned short* __restrict__ phiK, const unsigned short* __restrict__ Vb,
    float* __restrict__ KVc, float* __restrict__ ksc) {
  const int c = blockIdx.x;
  const int yv = blockIdx.y;
  const size_t base = (size_t)c * CHUNK * DHEAD;
  __shared__ unsigned short kt[128][136];   // k^T [d][t] (full)
  __shared__ unsigned short vt[64][136];    // v^T rows yv*64..+64
  __shared__ float csum[2][128];
  const int tid = threadIdx.x;
  const int wave = tid >> 6, lane = tid & 63;
  const int lrow = lane & 15, kgrp = lane >> 4;

  {
    int t = tid & 127, dp = tid >> 7;
#pragma unroll
    for (int i = 0; i < 8; ++i) {
      int d0 = (dp + 2 * i) * 8;
      uint4 k4 = *reinterpret_cast<const uint4*>(&phiK[base + (size_t)t * DHEAD + d0]);
      const unsigned short* kp = reinterpret_cast<const unsigned short*>(&k4);
#pragma unroll
      for (int j = 0; j < 8; ++j) kt[d0 + j][t] = kp[j];
    }
#pragma unroll
    for (int i = 0; i < 4; ++i) {
      int dl = (dp + 2 * i) * 8;             // 0..63 local dv
      uint4 v4 = *reinterpret_cast<const uint4*>(
          &Vb[base + (size_t)t * DHEAD + yv * 64 + dl]);
      const unsigned short* vp = reinterpret_cast<const unsigned short*>(&v4);
#pragma unroll
      for (int j = 0; j < 8; ++j) vt[dl + j][t] = vp[j];
    }
  }
  __syncthreads();

  f32x4 acc[8];
#pragma unroll
  for (int j = 0; j < 8; ++j) acc[j] = (f32x4)0.0f;
#pragma unroll
  for (int ks = 0; ks < 4; ++ks) {
    int t0 = ks * 32 + kgrp * 8;
    bf16x8 afrag = *reinterpret_cast<const bf16x8*>(&vt[wave * 16 + lrow][t0]);
#pragma unroll
    for (int tc = 0; tc < 8; ++tc) {
      bf16x8 bfrag = *reinterpret_cast<const bf16x8*>(&kt[tc * 16 + lrow][t0]);
      acc[tc] = __builtin_amdgcn_mfma_f32_16x16x32_bf16(afrag, bfrag, acc[tc], 0, 0, 0);
    }
  }
  float* KVout = KVc + (size_t)c * (DHEAD * DHEAD);   // [dv][d]
#pragma unroll
  for (int tc = 0; tc < 8; ++tc)
#pragma unroll
    for (int r = 0; r < 4; ++r) {
      int dv = yv * 64 + wave * 16 + kgrp * 4 + r;
      int d = tc * 16 + lrow;
      KVout[dv * DHEAD + d] = acc[tc][r];
    }
  if (yv == 0) {
    int d = tid & 127, hh = tid >> 7;
    float s = 0.0f;
    for (int t = hh * 64; t < hh * 64 + 64; ++t) s += bf2f(kt[d][t]);
    csum[hh][d] = s;
    __syncthreads();
    if (tid < 128) ksc[(size_t)c * DHEAD + tid] = csum[0][tid] + csum[1][tid];
  }
}

// ---------------- K3: exclusive prefix over chunks ----------------
__global__ __launch_bounds__(256) void prefix_kernel(
    const float* __restrict__ KVc, const float* __restrict__ ksc,
    unsigned short* __restrict__ KVp, float* __restrict__ ksp) {
  if (blockIdx.x < 256) {
    int id = blockIdx.x * 256 + threadIdx.x;
    int b = id >> 14;
    int e = id & 16383;
    size_t base = (size_t)b * NCHUNK * 16384 + e;
    float acc = 0.0f;
    for (int c = 0; c < NCHUNK; ++c) {
      KVp[base + (size_t)c * 16384] = f2bf(acc);
      acc += KVc[base + (size_t)c * 16384];
    }
  } else {
    for (int i = threadIdx.x; i < 512; i += 256) {
      int b = i >> 7, d = i & 127;
      size_t base = (size_t)b * NCHUNK * DHEAD + d;
      float acc = 0.0f;
      for (int c = 0; c < NCHUNK; ++c) {
        ksp[base + (size_t)c * DHEAD] = acc;
        acc += ksc[base + (size_t)c * DHEAD];
      }
    }
  }
}

// ---------------- K4: per-chunk output, split in q-row halves ----------------
__global__ __launch_bounds__(256) void out_kernel(
    const unsigned short* __restrict__ phiQ, const unsigned short* __restrict__ phiK,
    const unsigned short* __restrict__ Vb, const unsigned short* __restrict__ KVp,
    const float* __restrict__ ksp, float* __restrict__ outp) {
  const int c = blockIdx.x;
  const int h = blockIdx.y;
  const size_t kvbase = (size_t)c * CHUNK * DHEAD;
  const size_t qbase = kvbase + (size_t)h * 64 * DHEAD;
  __shared__ unsigned short qb[64][136];
  __shared__ unsigned short kb[128][136];
  __shared__ unsigned short vt[128][136];
  __shared__ float dsum[4][64];
  __shared__ float ks_l[128];
  const int tid = threadIdx.x;
  const int wave = tid >> 6, lane = tid & 63;
  const int lrow = lane & 15, kgrp = lane >> 4;

#pragma unroll
  for (int it = 0; it < 4; ++it) {
    int idx = it * 256 + tid;
    int t = idx >> 4;
    int d0 = (idx & 15) << 3;
    *reinterpret_cast<uint4*>(&qb[t][d0]) =
        *reinterpret_cast<const uint4*>(&phiQ[qbase + (size_t)t * DHEAD + d0]);
  }
  if (tid < 128) ks_l[tid] = ksp[(size_t)c * DHEAD + tid];
  if (h == 0) {
#pragma unroll
    for (int it = 0; it < 4; ++it) {
      int idx = it * 256 + tid;
      int t = idx >> 4;
      int d0 = (idx & 15) << 3;
      *reinterpret_cast<uint4*>(&kb[t][d0]) =
          *reinterpret_cast<const uint4*>(&phiK[kvbase + (size_t)t * DHEAD + d0]);
    }
    int t = tid & 63, dp = tid >> 6;
#pragma unroll
    for (int i = 0; i < 4; ++i) {
      int d0 = (dp + 4 * i) * 8;
      uint4 v4 = *reinterpret_cast<const uint4*>(&Vb[kvbase + (size_t)t * DHEAD + d0]);
      const unsigned short* vp = reinterpret_cast<const unsigned short*>(&v4);
#pragma unroll
      for (int j = 0; j < 8; ++j) vt[d0 + j][t] = vp[j];
    }
  } else {
#pragma unroll
    for (int it = 0; it < 8; ++it) {
      int idx = it * 256 + tid;
      int t = idx >> 4;
      int d0 = (idx & 15) << 3;
      *reinterpret_cast<uint4*>(&kb[t][d0]) =
          *reinterpret_cast<const uint4*>(&phiK[kvbase + (size_t)t * DHEAD + d0]);
    }
    int t = tid & 127, dp = tid >> 7;
#pragma unroll
    for (int i = 0; i < 8; ++i) {
      int d0 = (dp + 2 * i) * 8;
      uint4 v4 = *reinterpret_cast<const uint4*>(&Vb[kvbase + (size_t)t * DHEAD + d0]);
      const unsigned short* vp = reinterpret_cast<const unsigned short*>(&v4);
#pragma unroll
      for (int j = 0; j < 8; ++j) vt[d0 + j][t] = vp[j];
    }
  }
  __syncthreads();

  if (h == 0) {
    f32x4 sa[4];
#pragma unroll
    for (int i = 0; i < 4; ++i) sa[i] = (f32x4)0.0f;
#pragma unroll
    for (int ks = 0; ks < 4; ++ks) {
      int d0 = ks * 32 + kgrp * 8;
      bf16x8 af = *reinterpret_cast<const bf16x8*>(&qb[wave * 16 + lrow][d0]);
#pragma unroll
      for (int tc = 0; tc < 4; ++tc) {
        bf16x8 bf = *reinterpret_cast<const bf16x8*>(&kb[tc * 16 + lrow][d0]);
        sa[tc] = __builtin_amdgcn_mfma_f32_16x16x32_bf16(af, bf, sa[tc], 0, 0, 0);
      }
    }
    __syncthreads();
#pragma unroll
    for (int tc = 0; tc < 4; ++tc)
#pragma unroll
      for (int r = 0; r < 4; ++r) {
        int trow = wave * 16 + kgrp * 4 + r;
        int s = tc * 16 + lrow;
        kb[trow][s] = f2bf((s <= trow) ? sa[tc][r] : 0.0f);
      }
  } else {
    f32x4 sa[8];
#pragma unroll
    for (int i = 0; i < 8; ++i) sa[i] = (f32x4)0.0f;
#pragma unroll
    for (int ks = 0; ks < 4; ++ks) {
      int d0 = ks * 32 + kgrp * 8;
      bf16x8 af = *reinterpret_cast<const bf16x8*>(&qb[wave * 16 + lrow][d0]);
#pragma unroll
      for (int tc = 0; tc < 8; ++tc) {
        bf16x8 bf = *reinterpret_cast<const bf16x8*>(&kb[tc * 16 + lrow][d0]);
        sa[tc] = __builtin_amdgcn_mfma_f32_16x16x32_bf16(af, bf, sa[tc], 0, 0, 0);
      }
    }
    __syncthreads();
#pragma unroll
    for (int tc = 0; tc < 8; ++tc)
#pragma unroll
      for (int r = 0; r < 4; ++r) {
        int trow = wave * 16 + kgrp * 4 + r;
        int s = tc * 16 + lrow;
        kb[trow][s] = f2bf((s <= 64 + trow) ? sa[tc][r] : 0.0f);
      }
  }
  __syncthreads();   // P visible

  {
    int t = tid & 63, h4 = tid >> 6;
    float s = 0.0f;
    if (h4 < 2) {
      if (h4 == 0 || h == 1) {
        for (int j = h4 * 64; j < h4 * 64 + 64; ++j) s += bf2f(kb[t][j]);
      }
    } else {
      for (int j = (h4 - 2) * 64; j < (h4 - 2) * 64 + 64; ++j)
        s += bf2f(qb[t][j]) * ks_l[j];
    }
    dsum[h4][t] = s;
  }

  f32x4 acc[8];
#pragma unroll
  for (int i = 0; i < 8; ++i) acc[i] = (f32x4)0.0f;
  {
    const int nks = (h == 0) ? 2 : 4;
    for (int ks = 0; ks < nks; ++ks) {
      int t0 = ks * 32 + kgrp * 8;
      bf16x8 af = *reinterpret_cast<const bf16x8*>(&kb[wave * 16 + lrow][t0]);
#pragma unroll
      for (int tc = 0; tc < 8; ++tc) {
        bf16x8 bf = *reinterpret_cast<const bf16x8*>(&vt[tc * 16 + lrow][t0]);
        acc[tc] = __builtin_amdgcn_mfma_f32_16x16x32_bf16(af, bf, acc[tc], 0, 0, 0);
      }
    }
  }
  __syncthreads();

#pragma unroll
  for (int it = 0; it < 8; ++it) {
    int idx = it * 256 + tid;
    int dv = idx >> 4;
    int d0 = (idx & 15) << 3;
    *reinterpret_cast<uint4*>(&vt[dv][d0]) =
        *reinterpret_cast<const uint4*>(&KVp[(size_t)c * 16384 + (size_t)dv * DHEAD + d0]);
  }
  __syncthreads();

#pragma unroll
  for (int ks = 0; ks < 4; ++ks) {
    int d0 = ks * 32 + kgrp * 8;
    bf16x8 af = *reinterpret_cast<const bf16x8*>(&qb[wave * 16 + lrow][d0]);
#pragma unroll
    for (int tc = 0; tc < 8; ++tc) {
      bf16x8 bf = *reinterpret_cast<const bf16x8*>(&vt[tc * 16 + lrow][d0]);
      acc[tc] = __builtin_amdgcn_mfma_f32_16x16x32_bf16(af, bf, acc[tc], 0, 0, 0);
    }
  }

#pragma unroll
  for (int tc = 0; tc < 8; ++tc)
#pragma unroll
    for (int r = 0; r < 4; ++r) {
      int trow = wave * 16 + kgrp * 4 + r;
      int dv = tc * 16 + lrow;
      float den = dsum[0][trow] + dsum[1][trow] + dsum[2][trow] + dsum[3][trow];
      outp[qbase + (size_t)trow * DHEAD + dv] = acc[tc][r] / den;
    }
}

extern "C" void kernel_launch(void* const* d_in, const int* in_sizes, int n_in,
                              void* d_out, int out_size, void* d_ws, size_t ws_size,
                              hipStream_t stream) {
  const float* x  = (const float*)d_in[0];
  const float* Wq = (const float*)d_in[1];
  const float* Wk = (const float*)d_in[2];
  const float* Wv = (const float*)d_in[3];
  float* out = (float*)d_out;
  char* ws = (char*)d_ws;
  unsigned short* phiQ = (unsigned short*)(ws + 0);          // 4 MB
  unsigned short* phiK = (unsigned short*)(ws + 4194304);    // 4 MB
  unsigned short* Vb   = (unsigned short*)(ws + 8388608);    // 4 MB
  unsigned short* WT   = (unsigned short*)(ws + 12582912);   // 768 KB
  float*          KVc  = (float*)(ws + 13369344);            // 8 MB
  unsigned short* KVp  = (unsigned short*)(ws + 21757952);   // 4 MB
  float*          ksc  = (float*)(ws + 25952256);            // 64 KB
  float*          ksp  = (float*)(ws + 26017792);            // 64 KB

  transpose_w_kernel<<<1536, 256, 0, stream>>>(Wq, Wk, Wv, WT);
  proj_kernel<<<512, 256, 0, stream>>>(x, WT, phiQ, phiK, Vb);
  chunkkv_kernel<<<dim3(128, 2), 256, 0, stream>>>(phiK, Vb, KVc, ksc);
  prefix_kernel<<<257, 256, 0, stream>>>(KVc, ksc, KVp, ksp);
  out_kernel<<<dim3(128, 2), 256, 0, stream>>>(phiQ, phiK, Vb, KVp, ksp, out);
}